// Round 4
// baseline (1527.826 us; speedup 1.0000x reference)
//
#include <hip/hip_runtime.h>

#define N_NODES 100000
#define E_EDGES 1600000
#define D 128
#define SHIFT 7
#define BNODES 128                               // nodes per bin
#define NB ((N_NODES + BNODES - 1) / BNODES)     // 782 bins

#define CNT_CHUNK 2048
#define CNT_NBLK ((E_EDGES + CNT_CHUNK - 1) / CNT_CHUNK)   // 782
#define SCAT_CHUNK 16384
#define SCAT_NBLK ((E_EDGES + SCAT_CHUNK - 1) / SCAT_CHUNK) // 98

// ---- workspace layout (ints) ----
#define WS_CNT  0
#define WS_OFF  784
#define WS_POS  1568
#define WS_EBUF 2352
// total = 2352 + E ints ~= 6.4 MB

// -------- 1: coarse histogram (782 bins) --------
__global__ __launch_bounds__(256) void coarse_count(const int* __restrict__ dst,
                                                    int* __restrict__ cnt) {
    __shared__ int hist[NB];
    const int t = threadIdx.x;
    for (int i = t; i < NB; i += 256) hist[i] = 0;
    __syncthreads();
    const int e0 = blockIdx.x * CNT_CHUNK;
    for (int i = t; i < CNT_CHUNK; i += 256) {
        const int e = e0 + i;
        if (e < E_EDGES) atomicAdd(&hist[dst[e] >> SHIFT], 1);
    }
    __syncthreads();
    for (int b = t; b < NB; b += 256) {
        const int c = hist[b];
        if (c) atomicAdd(&cnt[b], c);
    }
}

// -------- 2: scan 782 bin counts (single block) --------
__global__ __launch_bounds__(1024) void coarse_scan(const int* __restrict__ cnt,
                                                    int* __restrict__ off,
                                                    int* __restrict__ pos) {
    __shared__ int buf[2][1024];
    const int t = threadIdx.x;
    const int v = (t < NB) ? cnt[t] : 0;
    int pi = 0;
    buf[0][t] = v;
    __syncthreads();
    #pragma unroll
    for (int o = 1; o < 1024; o <<= 1) {
        const int nv = buf[pi][t] + (t >= o ? buf[pi][t - o] : 0);
        buf[1 - pi][t] = nv;
        pi = 1 - pi;
        __syncthreads();
    }
    if (t < NB) {
        const int excl = buf[pi][t] - v;
        off[t] = excl;
        pos[t] = excl;
    }
    if (t == 0) off[NB] = E_EDGES;
}

// -------- 3: scatter packed (src<<7 | dst&127) grouped by coarse bin --------
// Two-phase LDS histogram: count -> reserve global run -> place. Each
// (block,bin) run (~84 B avg at 16K-edge chunks) is written by one CU in a
// tight window -> lines assemble in its L2 -> little write amplification.
__global__ __launch_bounds__(512) void coarse_scatter(const int* __restrict__ src,
                                                      const int* __restrict__ dst,
                                                      int* __restrict__ pos,
                                                      int* __restrict__ ebuf) {
    __shared__ int hist[NB];
    const int t = threadIdx.x;
    const int e0 = blockIdx.x * SCAT_CHUNK;
    for (int i = t; i < NB; i += 512) hist[i] = 0;
    __syncthreads();
    // phase 1: local count
    for (int i = t; i < SCAT_CHUNK; i += 512) {
        const int e = e0 + i;
        if (e < E_EDGES) atomicAdd(&hist[dst[e] >> SHIFT], 1);
    }
    __syncthreads();
    // phase 2: reserve global runs; hist[b] becomes the running global cursor
    for (int b = t; b < NB; b += 512) {
        const int c = hist[b];
        if (c) hist[b] = atomicAdd(&pos[b], c);
    }
    __syncthreads();
    // phase 3: place packed words
    for (int i = t; i < SCAT_CHUNK; i += 512) {
        const int e = e0 + i;
        if (e < E_EDGES) {
            const int d = dst[e];
            const int b = d >> SHIFT;
            const int p = atomicAdd(&hist[b], 1);   // LDS; returns global slot
            ebuf[p] = (src[e] << SHIFT) | (d & (BNODES - 1));
        }
    }
}

// -------- 4: fused per-bin gather + GEMM + epilogue --------
// One block per bin. 128x128 fp32 accumulator in LDS (64 KB); edges add
// h[src]*norm[src] into it via ds_add_f32; then GEMM against W (staged in
// 16-row LDS chunks) + norm/bias/leaky epilogue, written straight to out.
// LDS: 64K acc + 2K ew + 8K Wlds = 74 KB -> 2 blocks/CU (16 waves/CU).
__global__ __launch_bounds__(512, 4) void bin_fused(
    const float* __restrict__ h, const float* __restrict__ norm,
    const float* __restrict__ Wm, const float* __restrict__ bias,
    const int* __restrict__ off, const int* __restrict__ ebuf,
    float* __restrict__ out)
{
    __shared__ float acc[BNODES * D];      // 64 KB
    __shared__ int   ew[512];              // 2 KB staged edge words
    __shared__ float Wlds[16][D];          // 8 KB

    const int t = threadIdx.x;
    const int bin = blockIdx.x;
    const int nb = bin << SHIFT;

    // zero accumulator
    const float4 z = make_float4(0.f, 0.f, 0.f, 0.f);
    for (int i = t; i < BNODES * D / 4; i += 512)
        reinterpret_cast<float4*>(acc)[i] = z;

    const int cb = off[bin];
    const int ce = off[bin + 1];
    __syncthreads();

    // ---- gather phase ----
    const int grp = t >> 5;                // 16 groups of 32 lanes
    const int c0 = (t & 31) << 2;          // 4 cols per lane
    for (int base = cb; base < ce; base += 512) {
        int m = ce - base;
        if (m > 512) m = 512;
        if (t < m) ew[t] = ebuf[base + t];
        __syncthreads();
        int j = grp;
        for (; j + 16 < m; j += 32) {      // 2 edges in flight per group
            const int w0 = ew[j];
            const int w1 = ew[j + 16];
            const int s0 = w0 >> SHIFT, d0 = w0 & (BNODES - 1);
            const int s1 = w1 >> SHIFT, d1 = w1 & (BNODES - 1);
            const float n0 = norm[s0];
            const float n1 = norm[s1];
            const float4 h0 = *reinterpret_cast<const float4*>(h + s0 * D + c0);
            const float4 h1 = *reinterpret_cast<const float4*>(h + s1 * D + c0);
            float* a0 = acc + d0 * D + c0;
            float* a1 = acc + d1 * D + c0;
            atomicAdd(a0 + 0, h0.x * n0); atomicAdd(a0 + 1, h0.y * n0);
            atomicAdd(a0 + 2, h0.z * n0); atomicAdd(a0 + 3, h0.w * n0);
            atomicAdd(a1 + 0, h1.x * n1); atomicAdd(a1 + 1, h1.y * n1);
            atomicAdd(a1 + 2, h1.z * n1); atomicAdd(a1 + 3, h1.w * n1);
        }
        if (j < m) {
            const int w = ew[j];
            const int s = w >> SHIFT, dl = w & (BNODES - 1);
            const float nv = norm[s];
            const float4 hv = *reinterpret_cast<const float4*>(h + s * D + c0);
            float* ap = acc + dl * D + c0;
            atomicAdd(ap + 0, hv.x * nv); atomicAdd(ap + 1, hv.y * nv);
            atomicAdd(ap + 2, hv.z * nv); atomicAdd(ap + 3, hv.w * nv);
        }
        __syncthreads();
    }

    // ---- GEMM phase: thread t -> rows (t>>5)*8+{0..7}, cols (t&31)*4+{0..3}
    const int rg = (t >> 5) << 3;
    const int cc = (t & 31) << 2;
    float4 oacc[8];
    #pragma unroll
    for (int i = 0; i < 8; ++i) oacc[i] = z;

    for (int kc = 0; kc < D; kc += 16) {
        __syncthreads();                    // protect Wlds reuse (and acc on iter 0)
        {   // stage W[kc..kc+15][0..127]: 512 float4s, 1 per thread
            const int kk = t >> 5;
            const int c = (t & 31) << 2;
            *reinterpret_cast<float4*>(&Wlds[kk][c]) =
                *reinterpret_cast<const float4*>(Wm + (kc + kk) * D + c);
        }
        __syncthreads();

        #pragma unroll
        for (int k4 = 0; k4 < 16; k4 += 4) {
            float4 wv[4];
            #pragma unroll
            for (int kk = 0; kk < 4; ++kk)
                wv[kk] = *reinterpret_cast<const float4*>(&Wlds[k4 + kk][cc]);
            #pragma unroll
            for (int i = 0; i < 8; ++i) {
                const float4 gv = *reinterpret_cast<const float4*>(
                    acc + (rg + i) * D + kc + k4);
                oacc[i].x += gv.x * wv[0].x; oacc[i].y += gv.x * wv[0].y;
                oacc[i].z += gv.x * wv[0].z; oacc[i].w += gv.x * wv[0].w;
                oacc[i].x += gv.y * wv[1].x; oacc[i].y += gv.y * wv[1].y;
                oacc[i].z += gv.y * wv[1].z; oacc[i].w += gv.y * wv[1].w;
                oacc[i].x += gv.z * wv[2].x; oacc[i].y += gv.z * wv[2].y;
                oacc[i].z += gv.z * wv[2].z; oacc[i].w += gv.z * wv[2].w;
                oacc[i].x += gv.w * wv[3].x; oacc[i].y += gv.w * wv[3].y;
                oacc[i].z += gv.w * wv[3].z; oacc[i].w += gv.w * wv[3].w;
            }
        }
    }

    // ---- epilogue ----
    const float4 bb = *reinterpret_cast<const float4*>(bias + cc);
    #pragma unroll
    for (int i = 0; i < 8; ++i) {
        const int gr = nb + rg + i;
        if (gr < N_NODES) {
            const float nv = norm[gr];
            float4 v;
            v.x = oacc[i].x * nv + bb.x;
            v.y = oacc[i].y * nv + bb.y;
            v.z = oacc[i].z * nv + bb.z;
            v.w = oacc[i].w * nv + bb.w;
            v.x = v.x > 0.f ? v.x : 0.2f * v.x;
            v.y = v.y > 0.f ? v.y : 0.2f * v.y;
            v.z = v.z > 0.f ? v.z : 0.2f * v.z;
            v.w = v.w > 0.f ? v.w : 0.2f * v.w;
            *reinterpret_cast<float4*>(out + gr * D + cc) = v;
        }
    }
}

extern "C" void kernel_launch(void* const* d_in, const int* in_sizes, int n_in,
                              void* d_out, int out_size, void* d_ws, size_t ws_size,
                              hipStream_t stream) {
    const float* h    = (const float*)d_in[0];
    const float* norm = (const float*)d_in[1];
    const float* Wm   = (const float*)d_in[2];
    const float* bias = (const float*)d_in[3];
    const int*   src  = (const int*)d_in[4];
    const int*   dst  = (const int*)d_in[5];
    float* out = (float*)d_out;
    int* ws = (int*)d_ws;

    int* cnt  = ws + WS_CNT;
    int* off  = ws + WS_OFF;
    int* pos  = ws + WS_POS;
    int* ebuf = ws + WS_EBUF;

    hipMemsetAsync(cnt, 0, NB * sizeof(int), stream);

    coarse_count  <<<CNT_NBLK, 256, 0, stream>>>(dst, cnt);
    coarse_scan   <<<1, 1024, 0, stream>>>(cnt, off, pos);
    coarse_scatter<<<SCAT_NBLK, 512, 0, stream>>>(src, dst, pos, ebuf);
    bin_fused     <<<NB, 512, 0, stream>>>(h, norm, Wm, bias, off, ebuf, out);
}

// Round 5
// 317.625 us; speedup vs baseline: 4.8102x; 4.8102x over previous
//
#include <hip/hip_runtime.h>

#define N_NODES 100000
#define E_EDGES 1600000
#define D 128
#define SHIFT 7
#define BNODES 128
#define NB ((N_NODES + BNODES - 1) / BNODES)     // 782 bins

#define CNT_CHUNK 2048
#define CNT_NBLK ((E_EDGES + CNT_CHUNK - 1) / CNT_CHUNK)    // 782
#define SCAT_CHUNK 16384
#define SCAT_NBLK ((E_EDGES + SCAT_CHUNK - 1) / SCAT_CHUNK) // 98

// GEMM tiling (round-3 proven)
#define GROWS 64
#define KCH 32

// ---- workspace layout (int units) ----
#define WS_CNT   0                         // 784
#define WS_BOFF  784                       // NB+1 -> 784
#define WS_POS   1568                      // 784
#define WS_NOFF  2352                      // N+1 -> 100002
#define WS_EBUF  102400                    // E
#define WS_ESRC  (102400 + E_EDGES)        // E
#define WS_HS    (102400 + 2 * E_EDGES)    // N*D/2 ints (bf16 h*norm)
#define WS_FULL_INTS ((size_t)WS_HS + (size_t)N_NODES * D / 2)
#define WS_MID_INTS  ((size_t)WS_HS)

// ======================= CSR build =======================

__global__ __launch_bounds__(256) void coarse_count(const int* __restrict__ dst,
                                                    int* __restrict__ cnt) {
    __shared__ int hist[NB];
    const int t = threadIdx.x;
    for (int i = t; i < NB; i += 256) hist[i] = 0;
    __syncthreads();
    const int e0 = blockIdx.x * CNT_CHUNK;
    for (int i = t; i < CNT_CHUNK; i += 256) {
        const int e = e0 + i;
        if (e < E_EDGES) atomicAdd(&hist[dst[e] >> SHIFT], 1);
    }
    __syncthreads();
    for (int b = t; b < NB; b += 256) {
        const int c = hist[b];
        if (c) atomicAdd(&cnt[b], c);
    }
}

__global__ __launch_bounds__(1024) void coarse_scan(const int* __restrict__ cnt,
                                                    int* __restrict__ boff,
                                                    int* __restrict__ pos) {
    __shared__ int buf[2][1024];
    const int t = threadIdx.x;
    const int v = (t < NB) ? cnt[t] : 0;
    int pi = 0;
    buf[0][t] = v;
    __syncthreads();
    #pragma unroll
    for (int o = 1; o < 1024; o <<= 1) {
        const int nv = buf[pi][t] + (t >= o ? buf[pi][t - o] : 0);
        buf[1 - pi][t] = nv;
        pi = 1 - pi;
        __syncthreads();
    }
    if (t < NB) {
        const int excl = buf[pi][t] - v;
        boff[t] = excl;
        pos[t] = excl;
    }
    if (t == 0) boff[NB] = E_EDGES;
}

// scatter packed (src<<7 | dst&127) grouped by coarse bin; two-phase LDS hist
__global__ __launch_bounds__(512) void coarse_scatter(const int* __restrict__ src,
                                                      const int* __restrict__ dst,
                                                      int* __restrict__ pos,
                                                      int* __restrict__ ebuf) {
    __shared__ int hist[NB];
    const int t = threadIdx.x;
    const int e0 = blockIdx.x * SCAT_CHUNK;
    for (int i = t; i < NB; i += 512) hist[i] = 0;
    __syncthreads();
    for (int i = t; i < SCAT_CHUNK; i += 512) {
        const int e = e0 + i;
        if (e < E_EDGES) atomicAdd(&hist[dst[e] >> SHIFT], 1);
    }
    __syncthreads();
    for (int b = t; b < NB; b += 512) {
        const int c = hist[b];
        if (c) hist[b] = atomicAdd(&pos[b], c);
    }
    __syncthreads();
    for (int i = t; i < SCAT_CHUNK; i += 512) {
        const int e = e0 + i;
        if (e < E_EDGES) {
            const int d = dst[e];
            const int b = d >> SHIFT;
            const int p = atomicAdd(&hist[b], 1);
            ebuf[p] = (src[e] << SHIFT) | (d & (BNODES - 1));
        }
    }
}

// per-bin counting sort: bin-grouped ebuf -> per-node CSR (esrc) + node offsets.
// One block per bin; writes land in the bin's contiguous region -> write-amp ~1.
__global__ __launch_bounds__(256) void bin_sort(const int* __restrict__ boff,
                                                const int* __restrict__ ebuf,
                                                int* __restrict__ esrc,
                                                int* __restrict__ noff) {
    __shared__ int hist[BNODES];
    __shared__ int curs[BNODES];
    __shared__ int sbuf[2][BNODES];
    const int t = threadIdx.x;
    const int bin = blockIdx.x;
    if (t < BNODES) hist[t] = 0;
    __syncthreads();
    const int b0 = boff[bin];
    const int b1 = boff[bin + 1];
    for (int i = b0 + t; i < b1; i += 256)
        atomicAdd(&hist[ebuf[i] & (BNODES - 1)], 1);
    __syncthreads();
    if (t < BNODES) sbuf[0][t] = hist[t];
    __syncthreads();
    int pi = 0;
    #pragma unroll
    for (int o = 1; o < BNODES; o <<= 1) {
        if (t < BNODES)
            sbuf[1 - pi][t] = sbuf[pi][t] + (t >= o ? sbuf[pi][t - o] : 0);
        pi = 1 - pi;
        __syncthreads();
    }
    if (t < BNODES) {
        const int base = b0 + sbuf[pi][t] - hist[t];   // exclusive
        curs[t] = base;
        const int node = (bin << SHIFT) + t;
        if (node < N_NODES) noff[node] = base;
    }
    if (bin == 0 && t == 0) noff[N_NODES] = E_EDGES;
    __syncthreads();
    for (int i = b0 + t; i < b1; i += 256) {
        const int w = ebuf[i];
        const int p = atomicAdd(&curs[w & (BNODES - 1)], 1);
        esrc[p] = w >> SHIFT;
    }
}

// ======================= prep: hs = bf16(h * norm_src) =======================
__global__ __launch_bounds__(256) void prep_kernel(const float* __restrict__ h,
                                                   const float* __restrict__ norm,
                                                   unsigned short* __restrict__ hs) {
    const int idx = blockIdx.x * 256 + threadIdx.x;     // N*32 exactly
    const int node = idx >> 5;
    const int c = (idx & 31) << 2;
    const float nv = norm[node];
    const float4 v = *reinterpret_cast<const float4*>(h + node * D + c);
    float a[4] = {v.x * nv, v.y * nv, v.z * nv, v.w * nv};
    ushort4 o;
    unsigned short* op = reinterpret_cast<unsigned short*>(&o);
    #pragma unroll
    for (int i = 0; i < 4; ++i) {
        unsigned int u = __float_as_uint(a[i]);
        u += 0x7FFFu + ((u >> 16) & 1u);                // round-to-nearest-even
        op[i] = (unsigned short)(u >> 16);
    }
    *reinterpret_cast<ushort4*>(hs + node * D + c) = o;
}

// ======================= gathers =======================
__device__ __forceinline__ float4 bf4_to_f4(ushort4 u) {
    float4 f;
    f.x = __uint_as_float((unsigned int)u.x << 16);
    f.y = __uint_as_float((unsigned int)u.y << 16);
    f.z = __uint_as_float((unsigned int)u.z << 16);
    f.w = __uint_as_float((unsigned int)u.w << 16);
    return f;
}

__global__ __launch_bounds__(256) void gather_bf16(const unsigned short* __restrict__ hs,
                                                   const int* __restrict__ noff,
                                                   const int* __restrict__ esrc,
                                                   float* __restrict__ g) {
    const int t = threadIdx.x;
    const int node = blockIdx.x * 8 + (t >> 5);
    const int c = (t & 31) << 2;
    const int beg = noff[node];
    const int end = noff[node + 1];
    float4 acc = make_float4(0.f, 0.f, 0.f, 0.f);
    int i = beg;
    for (; i + 1 < end; i += 2) {                      // 2 rows in flight
        const int s0 = esrc[i];
        const int s1 = esrc[i + 1];
        const float4 a = bf4_to_f4(*reinterpret_cast<const ushort4*>(hs + s0 * D + c));
        const float4 b = bf4_to_f4(*reinterpret_cast<const ushort4*>(hs + s1 * D + c));
        acc.x += a.x + b.x;
        acc.y += a.y + b.y;
        acc.z += a.z + b.z;
        acc.w += a.w + b.w;
    }
    if (i < end) {
        const int s = esrc[i];
        const float4 a = bf4_to_f4(*reinterpret_cast<const ushort4*>(hs + s * D + c));
        acc.x += a.x; acc.y += a.y; acc.z += a.z; acc.w += a.w;
    }
    *reinterpret_cast<float4*>(g + node * D + c) = acc;
}

__global__ __launch_bounds__(256) void gather_fp32(const float* __restrict__ h,
                                                   const float* __restrict__ norm,
                                                   const int* __restrict__ noff,
                                                   const int* __restrict__ esrc,
                                                   float* __restrict__ g) {
    const int t = threadIdx.x;
    const int node = blockIdx.x * 8 + (t >> 5);
    const int c = (t & 31) << 2;
    const int beg = noff[node];
    const int end = noff[node + 1];
    float4 acc = make_float4(0.f, 0.f, 0.f, 0.f);
    for (int i = beg; i < end; ++i) {
        const int s = esrc[i];
        const float nv = norm[s];
        const float4 hv = *reinterpret_cast<const float4*>(h + s * D + c);
        acc.x += hv.x * nv;
        acc.y += hv.y * nv;
        acc.z += hv.z * nv;
        acc.w += hv.w * nv;
    }
    *reinterpret_cast<float4*>(g + node * D + c) = acc;
}

// ======================= tier-0 fallback: atomic scatter =======================
__global__ __launch_bounds__(256) void scatter_kernel(
    const float* __restrict__ h, const float* __restrict__ norm,
    const int* __restrict__ src, const int* __restrict__ dst,
    float* __restrict__ g)
{
    const int idx = blockIdx.x * 256 + threadIdx.x;
    const int e = idx >> 5;
    const int c = (idx & 31) << 2;
    const int s = src[e];
    const int d = dst[e];
    const float nv = norm[s];
    const float4 hv = *reinterpret_cast<const float4*>(h + s * D + c);
    float* gp = g + d * D + c;
    atomicAdd(gp + 0, hv.x * nv);
    atomicAdd(gp + 1, hv.y * nv);
    atomicAdd(gp + 2, hv.z * nv);
    atomicAdd(gp + 3, hv.w * nv);
}

// ======================= GEMM + epilogue (round-3 proven) =======================
__global__ __launch_bounds__(256) void gemm_epilogue(
    float* __restrict__ out, const float* __restrict__ Wm,
    const float* __restrict__ bias, const float* __restrict__ norm)
{
    __shared__ float gs[GROWS][D + 4];
    __shared__ float Wlds[KCH][D];
    const int t = threadIdx.x;
    const int row0 = blockIdx.x * GROWS;

    #pragma unroll
    for (int p = 0; p < 8; ++p) {
        const int i = p * 256 + t;
        const int r = i >> 5;
        const int c = (i & 31) << 2;
        int gr = row0 + r;
        if (gr >= N_NODES) gr = N_NODES - 1;
        const float4 v = *reinterpret_cast<const float4*>(out + gr * D + c);
        *reinterpret_cast<float4*>(&gs[r][c]) = v;
    }

    const int rg = (t >> 5) * 8;
    const int cb = (t & 31) << 2;

    float4 acc[8];
    #pragma unroll
    for (int i = 0; i < 8; ++i) acc[i] = make_float4(0.f, 0.f, 0.f, 0.f);

    for (int kc = 0; kc < D; kc += KCH) {
        __syncthreads();
        #pragma unroll
        for (int p = 0; p < 4; ++p) {
            const int i = p * 256 + t;
            const int kk = i >> 5;
            const int c = (i & 31) << 2;
            *reinterpret_cast<float4*>(&Wlds[kk][c]) =
                *reinterpret_cast<const float4*>(Wm + (kc + kk) * D + c);
        }
        __syncthreads();

        #pragma unroll
        for (int k4 = 0; k4 < KCH; k4 += 4) {
            float4 wv[4];
            #pragma unroll
            for (int kk = 0; kk < 4; ++kk)
                wv[kk] = *reinterpret_cast<const float4*>(&Wlds[k4 + kk][cb]);
            #pragma unroll
            for (int i = 0; i < 8; ++i) {
                const float4 gv = *reinterpret_cast<const float4*>(&gs[rg + i][kc + k4]);
                acc[i].x += gv.x * wv[0].x; acc[i].y += gv.x * wv[0].y;
                acc[i].z += gv.x * wv[0].z; acc[i].w += gv.x * wv[0].w;
                acc[i].x += gv.y * wv[1].x; acc[i].y += gv.y * wv[1].y;
                acc[i].z += gv.y * wv[1].z; acc[i].w += gv.y * wv[1].w;
                acc[i].x += gv.z * wv[2].x; acc[i].y += gv.z * wv[2].y;
                acc[i].z += gv.z * wv[2].z; acc[i].w += gv.z * wv[2].w;
                acc[i].x += gv.w * wv[3].x; acc[i].y += gv.w * wv[3].y;
                acc[i].z += gv.w * wv[3].z; acc[i].w += gv.w * wv[3].w;
            }
        }
    }

    const float4 b = *reinterpret_cast<const float4*>(bias + cb);
    #pragma unroll
    for (int i = 0; i < 8; ++i) {
        const int gr = row0 + rg + i;
        if (gr < N_NODES) {
            const float nv = norm[gr];
            float4 v;
            v.x = acc[i].x * nv + b.x;
            v.y = acc[i].y * nv + b.y;
            v.z = acc[i].z * nv + b.z;
            v.w = acc[i].w * nv + b.w;
            v.x = v.x > 0.f ? v.x : 0.2f * v.x;
            v.y = v.y > 0.f ? v.y : 0.2f * v.y;
            v.z = v.z > 0.f ? v.z : 0.2f * v.z;
            v.w = v.w > 0.f ? v.w : 0.2f * v.w;
            *reinterpret_cast<float4*>(out + gr * D + cb) = v;
        }
    }
}

extern "C" void kernel_launch(void* const* d_in, const int* in_sizes, int n_in,
                              void* d_out, int out_size, void* d_ws, size_t ws_size,
                              hipStream_t stream) {
    const float* h    = (const float*)d_in[0];
    const float* norm = (const float*)d_in[1];
    const float* Wm   = (const float*)d_in[2];
    const float* bias = (const float*)d_in[3];
    const int*   src  = (const int*)d_in[4];
    const int*   dst  = (const int*)d_in[5];
    float* out = (float*)d_out;
    int* ws = (int*)d_ws;

    // ws_size is constant across calls -> tier choice is deterministic (graph-safe)
    if (ws_size >= WS_MID_INTS * 4) {
        int* cnt  = ws + WS_CNT;
        int* boff = ws + WS_BOFF;
        int* pos  = ws + WS_POS;
        int* noff = ws + WS_NOFF;
        int* ebuf = ws + WS_EBUF;
        int* esrc = ws + WS_ESRC;
        unsigned short* hs = (unsigned short*)(ws + WS_HS);
        const bool use_bf16 = (ws_size >= WS_FULL_INTS * 4);

        hipMemsetAsync(cnt, 0, NB * sizeof(int), stream);
        if (use_bf16)
            prep_kernel<<<(N_NODES * 32) / 256, 256, 0, stream>>>(h, norm, hs);
        coarse_count  <<<CNT_NBLK, 256, 0, stream>>>(dst, cnt);
        coarse_scan   <<<1, 1024, 0, stream>>>(cnt, boff, pos);
        coarse_scatter<<<SCAT_NBLK, 512, 0, stream>>>(src, dst, pos, ebuf);
        bin_sort      <<<NB, 256, 0, stream>>>(boff, ebuf, esrc, noff);
        if (use_bf16)
            gather_bf16<<<N_NODES / 8, 256, 0, stream>>>(hs, noff, esrc, out);
        else
            gather_fp32<<<N_NODES / 8, 256, 0, stream>>>(h, norm, noff, esrc, out);
    } else {
        // tier 0: zero-ws atomic scatter
        hipMemsetAsync(out, 0, (size_t)N_NODES * D * sizeof(float), stream);
        scatter_kernel<<<(E_EDGES * 32) / 256, 256, 0, stream>>>(h, norm, src, dst, out);
    }

    gemm_epilogue<<<(N_NODES + GROWS - 1) / GROWS, 256, 0, stream>>>(out, Wm, bias, norm);
}

// Round 6
// 287.799 us; speedup vs baseline: 5.3086x; 1.1036x over previous
//
#include <hip/hip_runtime.h>

#define N_NODES 100000
#define E_EDGES 1600000
#define D 128
#define SHIFT 7
#define BNODES 128
#define NB ((N_NODES + BNODES - 1) / BNODES)     // 782 bins

#define CNT_CHUNK 2048
#define CNT_NBLK ((E_EDGES + CNT_CHUNK - 1) / CNT_CHUNK)    // 782
#define SCAT_CHUNK 16384
#define SCAT_NBLK ((E_EDGES + SCAT_CHUNK - 1) / SCAT_CHUNK) // 98

// fp32-GEMM tiling (tier-0 fallback only)
#define GROWS 64
#define KCH 32

typedef _Float16 f16x8 __attribute__((ext_vector_type(8)));
typedef float    f32x4 __attribute__((ext_vector_type(4)));

// ---- workspace layout (int units) ----
#define WS_CNT   0
#define WS_BOFF  784
#define WS_POS   1568
#define WS_NOFF  2352                      // N+1
#define WS_EBUF  102400                    // E   (first 8192 ints reused as Whs after bin_sort)
#define WS_ESRC  (102400 + E_EDGES)        // E
#define WS_HS    (102400 + 2 * E_EDGES)    // N*D/2 ints (bf16 h*norm)
#define WS_FULL_INTS ((size_t)WS_HS + (size_t)N_NODES * D / 2)
#define WS_MID_INTS  ((size_t)WS_HS)

// ======================= CSR build =======================

__global__ __launch_bounds__(256) void coarse_count(const int* __restrict__ dst,
                                                    int* __restrict__ cnt) {
    __shared__ int hist[NB];
    const int t = threadIdx.x;
    for (int i = t; i < NB; i += 256) hist[i] = 0;
    __syncthreads();
    const int e0 = blockIdx.x * CNT_CHUNK;
    for (int i = t; i < CNT_CHUNK; i += 256) {
        const int e = e0 + i;
        if (e < E_EDGES) atomicAdd(&hist[dst[e] >> SHIFT], 1);
    }
    __syncthreads();
    for (int b = t; b < NB; b += 256) {
        const int c = hist[b];
        if (c) atomicAdd(&cnt[b], c);
    }
}

__global__ __launch_bounds__(1024) void coarse_scan(const int* __restrict__ cnt,
                                                    int* __restrict__ boff,
                                                    int* __restrict__ pos) {
    __shared__ int buf[2][1024];
    const int t = threadIdx.x;
    const int v = (t < NB) ? cnt[t] : 0;
    int pi = 0;
    buf[0][t] = v;
    __syncthreads();
    #pragma unroll
    for (int o = 1; o < 1024; o <<= 1) {
        const int nv = buf[pi][t] + (t >= o ? buf[pi][t - o] : 0);
        buf[1 - pi][t] = nv;
        pi = 1 - pi;
        __syncthreads();
    }
    if (t < NB) {
        const int excl = buf[pi][t] - v;
        boff[t] = excl;
        pos[t] = excl;
    }
    if (t == 0) boff[NB] = E_EDGES;
}

__global__ __launch_bounds__(512) void coarse_scatter(const int* __restrict__ src,
                                                      const int* __restrict__ dst,
                                                      int* __restrict__ pos,
                                                      int* __restrict__ ebuf) {
    __shared__ int hist[NB];
    const int t = threadIdx.x;
    const int e0 = blockIdx.x * SCAT_CHUNK;
    for (int i = t; i < NB; i += 512) hist[i] = 0;
    __syncthreads();
    for (int i = t; i < SCAT_CHUNK; i += 512) {
        const int e = e0 + i;
        if (e < E_EDGES) atomicAdd(&hist[dst[e] >> SHIFT], 1);
    }
    __syncthreads();
    for (int b = t; b < NB; b += 512) {
        const int c = hist[b];
        if (c) hist[b] = atomicAdd(&pos[b], c);
    }
    __syncthreads();
    for (int i = t; i < SCAT_CHUNK; i += 512) {
        const int e = e0 + i;
        if (e < E_EDGES) {
            const int d = dst[e];
            const int b = d >> SHIFT;
            const int p = atomicAdd(&hist[b], 1);
            ebuf[p] = (src[e] << SHIFT) | (d & (BNODES - 1));
        }
    }
}

__global__ __launch_bounds__(256) void bin_sort(const int* __restrict__ boff,
                                                const int* __restrict__ ebuf,
                                                int* __restrict__ esrc,
                                                int* __restrict__ noff) {
    __shared__ int hist[BNODES];
    __shared__ int curs[BNODES];
    __shared__ int sbuf[2][BNODES];
    const int t = threadIdx.x;
    const int bin = blockIdx.x;
    if (t < BNODES) hist[t] = 0;
    __syncthreads();
    const int b0 = boff[bin];
    const int b1 = boff[bin + 1];
    for (int i = b0 + t; i < b1; i += 256)
        atomicAdd(&hist[ebuf[i] & (BNODES - 1)], 1);
    __syncthreads();
    if (t < BNODES) sbuf[0][t] = hist[t];
    __syncthreads();
    int pi = 0;
    #pragma unroll
    for (int o = 1; o < BNODES; o <<= 1) {
        if (t < BNODES)
            sbuf[1 - pi][t] = sbuf[pi][t] + (t >= o ? sbuf[pi][t - o] : 0);
        pi = 1 - pi;
        __syncthreads();
    }
    if (t < BNODES) {
        const int base = b0 + sbuf[pi][t] - hist[t];
        curs[t] = base;
        const int node = (bin << SHIFT) + t;
        if (node < N_NODES) noff[node] = base;
    }
    if (bin == 0 && t == 0) noff[N_NODES] = E_EDGES;
    __syncthreads();
    for (int i = b0 + t; i < b1; i += 256) {
        const int w = ebuf[i];
        const int p = atomicAdd(&curs[w & (BNODES - 1)], 1);
        esrc[p] = w >> SHIFT;
    }
}

// ======================= prep: hs = bf16(h * norm_src) =======================
__global__ __launch_bounds__(256) void prep_kernel(const float* __restrict__ h,
                                                   const float* __restrict__ norm,
                                                   unsigned short* __restrict__ hs) {
    const int idx = blockIdx.x * 256 + threadIdx.x;
    const int node = idx >> 5;
    const int c = (idx & 31) << 2;
    const float nv = norm[node];
    const float4 v = *reinterpret_cast<const float4*>(h + node * D + c);
    float a[4] = {v.x * nv, v.y * nv, v.z * nv, v.w * nv};
    ushort4 o;
    unsigned short* op = reinterpret_cast<unsigned short*>(&o);
    #pragma unroll
    for (int i = 0; i < 4; ++i) {
        unsigned int u = __float_as_uint(a[i]);
        u += 0x7FFFu + ((u >> 16) & 1u);
        op[i] = (unsigned short)(u >> 16);
    }
    *reinterpret_cast<ushort4*>(hs + node * D + c) = o;
}

// ======================= wprep: swizzle W -> f16 B-fragments =======================
// Whs[(kiter*8+nt)*64 + lane] = 8 halves: W[kiter*32 + (lane>>4)*8 + j][nt*16 + (lane&15)]
// 2048 threads, one 16B fragment each. Written into ebuf's space (dead after bin_sort).
__global__ __launch_bounds__(256) void wprep_kernel(const float* __restrict__ Wm,
                                                    f16x8* __restrict__ Whs) {
    const int tid = blockIdx.x * 256 + threadIdx.x;   // 0..2047
    const int kiter = tid >> 9;
    const int nt = (tid >> 6) & 7;
    const int lane = tid & 63;
    const int q = lane >> 4;
    const int col = nt * 16 + (lane & 15);
    f16x8 v;
    #pragma unroll
    for (int j = 0; j < 8; ++j)
        v[j] = (_Float16)Wm[(kiter * 32 + q * 8 + j) * D + col];
    Whs[tid] = v;
}

// ======================= gathers =======================
__device__ __forceinline__ float4 bf4_to_f4(ushort4 u) {
    float4 f;
    f.x = __uint_as_float((unsigned int)u.x << 16);
    f.y = __uint_as_float((unsigned int)u.y << 16);
    f.z = __uint_as_float((unsigned int)u.z << 16);
    f.w = __uint_as_float((unsigned int)u.w << 16);
    return f;
}

__global__ __launch_bounds__(256) void gather_bf16(const unsigned short* __restrict__ hs,
                                                   const int* __restrict__ noff,
                                                   const int* __restrict__ esrc,
                                                   float* __restrict__ g) {
    const int t = threadIdx.x;
    const int node = blockIdx.x * 8 + (t >> 5);
    const int c = (t & 31) << 2;
    const int beg = noff[node];
    const int end = noff[node + 1];
    float4 acc = make_float4(0.f, 0.f, 0.f, 0.f);
    int i = beg;
    for (; i + 1 < end; i += 2) {
        const int s0 = esrc[i];
        const int s1 = esrc[i + 1];
        const float4 a = bf4_to_f4(*reinterpret_cast<const ushort4*>(hs + s0 * D + c));
        const float4 b = bf4_to_f4(*reinterpret_cast<const ushort4*>(hs + s1 * D + c));
        acc.x += a.x + b.x;
        acc.y += a.y + b.y;
        acc.z += a.z + b.z;
        acc.w += a.w + b.w;
    }
    if (i < end) {
        const int s = esrc[i];
        const float4 a = bf4_to_f4(*reinterpret_cast<const ushort4*>(hs + s * D + c));
        acc.x += a.x; acc.y += a.y; acc.z += a.z; acc.w += a.w;
    }
    *reinterpret_cast<float4*>(g + node * D + c) = acc;
}

__global__ __launch_bounds__(256) void gather_fp32(const float* __restrict__ h,
                                                   const float* __restrict__ norm,
                                                   const int* __restrict__ noff,
                                                   const int* __restrict__ esrc,
                                                   float* __restrict__ g) {
    const int t = threadIdx.x;
    const int node = blockIdx.x * 8 + (t >> 5);
    const int c = (t & 31) << 2;
    const int beg = noff[node];
    const int end = noff[node + 1];
    float4 acc = make_float4(0.f, 0.f, 0.f, 0.f);
    for (int i = beg; i < end; ++i) {
        const int s = esrc[i];
        const float nv = norm[s];
        const float4 hv = *reinterpret_cast<const float4*>(h + s * D + c);
        acc.x += hv.x * nv;
        acc.y += hv.y * nv;
        acc.z += hv.z * nv;
        acc.w += hv.w * nv;
    }
    *reinterpret_cast<float4*>(g + node * D + c) = acc;
}

// ======================= tier-0 fallback: atomic scatter =======================
__global__ __launch_bounds__(256) void scatter_kernel(
    const float* __restrict__ h, const float* __restrict__ norm,
    const int* __restrict__ src, const int* __restrict__ dst,
    float* __restrict__ g)
{
    const int idx = blockIdx.x * 256 + threadIdx.x;
    const int e = idx >> 5;
    const int c = (idx & 31) << 2;
    const int s = src[e];
    const int d = dst[e];
    const float nv = norm[s];
    const float4 hv = *reinterpret_cast<const float4*>(h + s * D + c);
    float* gp = g + d * D + c;
    atomicAdd(gp + 0, hv.x * nv);
    atomicAdd(gp + 1, hv.y * nv);
    atomicAdd(gp + 2, hv.z * nv);
    atomicAdd(gp + 3, hv.w * nv);
}

// ======================= MFMA GEMM + epilogue =======================
// out = leaky_relu((g @ W) * norm + bias), in place. 64 rows/block, 4 waves,
// wave = 16-row strip x 128 cols = 8 acc tiles of 16x16 (f32x4 each).
// A: fp32 g rows -> cvt f16 in regs (A[m=lane&15][k=quad*8+j]).
// B: pre-swizzled Whs staged whole in 32 KB LDS, one ds_read_b128 per frag.
// In-place safe: a wave reads only its own strip's rows, stores after K-loop.
__global__ __launch_bounds__(256) void gemm_mfma(
    float* __restrict__ out, const f16x8* __restrict__ Whs,
    const float* __restrict__ bias, const float* __restrict__ norm)
{
    __shared__ f16x8 Wlds[2048];           // 32 KB
    const int t = threadIdx.x;
    const int row0 = blockIdx.x * 64;

    // stage swizzled W: 2048 fragments = 8 float4 copies/thread
    #pragma unroll
    for (int p = 0; p < 8; ++p)
        reinterpret_cast<float4*>(Wlds)[p * 256 + t] =
            reinterpret_cast<const float4*>(Whs)[p * 256 + t];
    __syncthreads();

    const int lane = t & 63;
    const int strip = t >> 6;              // wave id 0..3
    const int q = lane >> 4;
    const int l15 = lane & 15;

    int mrow = row0 + strip * 16 + l15;    // A-row this lane supplies
    if (mrow >= N_NODES) mrow = N_NODES - 1;   // clamp; results discarded

    f32x4 acc[8];
    #pragma unroll
    for (int i = 0; i < 8; ++i) acc[i] = (f32x4){0.f, 0.f, 0.f, 0.f};

    #pragma unroll
    for (int kiter = 0; kiter < 4; ++kiter) {
        const float* gp = out + mrow * D + kiter * 32 + q * 8;
        const float4 ga = *reinterpret_cast<const float4*>(gp);
        const float4 gb = *reinterpret_cast<const float4*>(gp + 4);
        f16x8 a;
        a[0] = (_Float16)ga.x; a[1] = (_Float16)ga.y;
        a[2] = (_Float16)ga.z; a[3] = (_Float16)ga.w;
        a[4] = (_Float16)gb.x; a[5] = (_Float16)gb.y;
        a[6] = (_Float16)gb.z; a[7] = (_Float16)gb.w;
        #pragma unroll
        for (int nt = 0; nt < 8; ++nt) {
            const f16x8 b = Wlds[(kiter * 8 + nt) * 64 + lane];
            acc[nt] = __builtin_amdgcn_mfma_f32_16x16x32_f16(a, b, acc[nt], 0, 0, 0);
        }
    }

    // epilogue: D tile mapping col=lane&15 (n), row=q*4+reg (m)
    float nrm[4];
    int mr[4];
    #pragma unroll
    for (int rgi = 0; rgi < 4; ++rgi) {
        mr[rgi] = row0 + strip * 16 + q * 4 + rgi;
        nrm[rgi] = (mr[rgi] < N_NODES) ? norm[mr[rgi]] : 0.f;
    }
    #pragma unroll
    for (int nt = 0; nt < 8; ++nt) {
        const int col = nt * 16 + l15;
        const float bc = bias[col];
        #pragma unroll
        for (int rgi = 0; rgi < 4; ++rgi) {
            if (mr[rgi] < N_NODES) {
                float v = acc[nt][rgi] * nrm[rgi] + bc;
                v = v > 0.f ? v : 0.2f * v;
                out[mr[rgi] * D + col] = v;
            }
        }
    }
}

// ======================= fp32 GEMM (tier-0 fallback only) =======================
__global__ __launch_bounds__(256) void gemm_epilogue(
    float* __restrict__ out, const float* __restrict__ Wm,
    const float* __restrict__ bias, const float* __restrict__ norm)
{
    __shared__ float gs[GROWS][D + 4];
    __shared__ float Wlds[KCH][D];
    const int t = threadIdx.x;
    const int row0 = blockIdx.x * GROWS;

    #pragma unroll
    for (int p = 0; p < 8; ++p) {
        const int i = p * 256 + t;
        const int r = i >> 5;
        const int c = (i & 31) << 2;
        int gr = row0 + r;
        if (gr >= N_NODES) gr = N_NODES - 1;
        const float4 v = *reinterpret_cast<const float4*>(out + gr * D + c);
        *reinterpret_cast<float4*>(&gs[r][c]) = v;
    }

    const int rg = (t >> 5) * 8;
    const int cb = (t & 31) << 2;

    float4 acc[8];
    #pragma unroll
    for (int i = 0; i < 8; ++i) acc[i] = make_float4(0.f, 0.f, 0.f, 0.f);

    for (int kc = 0; kc < D; kc += KCH) {
        __syncthreads();
        #pragma unroll
        for (int p = 0; p < 4; ++p) {
            const int i = p * 256 + t;
            const int kk = i >> 5;
            const int c = (i & 31) << 2;
            *reinterpret_cast<float4*>(&Wlds[kk][c]) =
                *reinterpret_cast<const float4*>(Wm + (kc + kk) * D + c);
        }
        __syncthreads();

        #pragma unroll
        for (int k4 = 0; k4 < KCH; k4 += 4) {
            float4 wv[4];
            #pragma unroll
            for (int kk = 0; kk < 4; ++kk)
                wv[kk] = *reinterpret_cast<const float4*>(&Wlds[k4 + kk][cb]);
            #pragma unroll
            for (int i = 0; i < 8; ++i) {
                const float4 gv = *reinterpret_cast<const float4*>(&gs[rg + i][kc + k4]);
                acc[i].x += gv.x * wv[0].x; acc[i].y += gv.x * wv[0].y;
                acc[i].z += gv.x * wv[0].z; acc[i].w += gv.x * wv[0].w;
                acc[i].x += gv.y * wv[1].x; acc[i].y += gv.y * wv[1].y;
                acc[i].z += gv.y * wv[1].z; acc[i].w += gv.y * wv[1].w;
                acc[i].x += gv.z * wv[2].x; acc[i].y += gv.z * wv[2].y;
                acc[i].z += gv.z * wv[2].z; acc[i].w += gv.z * wv[2].w;
                acc[i].x += gv.w * wv[3].x; acc[i].y += gv.w * wv[3].y;
                acc[i].z += gv.w * wv[3].z; acc[i].w += gv.w * wv[3].w;
            }
        }
    }

    const float4 b = *reinterpret_cast<const float4*>(bias + cb);
    #pragma unroll
    for (int i = 0; i < 8; ++i) {
        const int gr = row0 + rg + i;
        if (gr < N_NODES) {
            const float nv = norm[gr];
            float4 v;
            v.x = acc[i].x * nv + b.x;
            v.y = acc[i].y * nv + b.y;
            v.z = acc[i].z * nv + b.z;
            v.w = acc[i].w * nv + b.w;
            v.x = v.x > 0.f ? v.x : 0.2f * v.x;
            v.y = v.y > 0.f ? v.y : 0.2f * v.y;
            v.z = v.z > 0.f ? v.z : 0.2f * v.z;
            v.w = v.w > 0.f ? v.w : 0.2f * v.w;
            *reinterpret_cast<float4*>(out + gr * D + cb) = v;
        }
    }
}

extern "C" void kernel_launch(void* const* d_in, const int* in_sizes, int n_in,
                              void* d_out, int out_size, void* d_ws, size_t ws_size,
                              hipStream_t stream) {
    const float* h    = (const float*)d_in[0];
    const float* norm = (const float*)d_in[1];
    const float* Wm   = (const float*)d_in[2];
    const float* bias = (const float*)d_in[3];
    const int*   src  = (const int*)d_in[4];
    const int*   dst  = (const int*)d_in[5];
    float* out = (float*)d_out;
    int* ws = (int*)d_ws;

    if (ws_size >= WS_MID_INTS * 4) {
        int* cnt  = ws + WS_CNT;
        int* boff = ws + WS_BOFF;
        int* pos  = ws + WS_POS;
        int* noff = ws + WS_NOFF;
        int* ebuf = ws + WS_EBUF;
        int* esrc = ws + WS_ESRC;
        unsigned short* hs = (unsigned short*)(ws + WS_HS);
        f16x8* Whs = (f16x8*)ebuf;         // reuses ebuf after bin_sort (serial stream)
        const bool use_bf16 = (ws_size >= WS_FULL_INTS * 4);

        hipMemsetAsync(cnt, 0, NB * sizeof(int), stream);
        if (use_bf16)
            prep_kernel<<<(N_NODES * 32) / 256, 256, 0, stream>>>(h, norm, hs);
        coarse_count  <<<CNT_NBLK, 256, 0, stream>>>(dst, cnt);
        coarse_scan   <<<1, 1024, 0, stream>>>(cnt, boff, pos);
        coarse_scatter<<<SCAT_NBLK, 512, 0, stream>>>(src, dst, pos, ebuf);
        bin_sort      <<<NB, 256, 0, stream>>>(boff, ebuf, esrc, noff);
        wprep_kernel  <<<8, 256, 0, stream>>>(Wm, Whs);   // overwrites ebuf[0..8191]
        if (use_bf16)
            gather_bf16<<<N_NODES / 8, 256, 0, stream>>>(hs, noff, esrc, out);
        else
            gather_fp32<<<N_NODES / 8, 256, 0, stream>>>(h, norm, noff, esrc, out);
        gemm_mfma<<<(N_NODES + 63) / 64, 256, 0, stream>>>(out, Whs, bias, norm);
    } else {
        hipMemsetAsync(out, 0, (size_t)N_NODES * D * sizeof(float), stream);
        scatter_kernel<<<(E_EDGES * 32) / 256, 256, 0, stream>>>(h, norm, src, dst, out);
        gemm_epilogue<<<(N_NODES + GROWS - 1) / GROWS, 256, 0, stream>>>(out, Wm, bias, norm);
    }
}

// Round 7
// 254.616 us; speedup vs baseline: 6.0005x; 1.1303x over previous
//
#include <hip/hip_runtime.h>

#define N_NODES 100000
#define E_EDGES 1600000
#define D 128
#define SHIFT 7
#define BNODES 128
#define NB ((N_NODES + BNODES - 1) / BNODES)     // 782 bins

#define CNT_CHUNK 2048
#define CNT_NBLK ((E_EDGES + CNT_CHUNK - 1) / CNT_CHUNK)    // 782
#define PREP_NBLK (N_NODES * 32 / 256)                      // 12500
#define SCAT_CHUNK 16384
#define SCAT_NBLK ((E_EDGES + SCAT_CHUNK - 1) / SCAT_CHUNK) // 98
#define GATH_NBLK (N_NODES / 16)                            // 6250
#define GATH32_NBLK (N_NODES / 8)                           // 12500

// fp32-GEMM tiling (tier-0 fallback only)
#define GROWS 64
#define KCH 32

typedef _Float16       f16x8  __attribute__((ext_vector_type(8)));
typedef float          f32x4  __attribute__((ext_vector_type(4)));
typedef unsigned short u16x8  __attribute__((ext_vector_type(8)));

// ---- workspace layout (int units) ----
#define WS_CNT   0
#define WS_BOFF  784
#define WS_POS   1568
#define WS_NOFF  2352                      // N+1
#define WS_EBUF  102400                    // E   (first 8192 ints reused as Whs after bin_sort)
#define WS_ESRC  (102400 + E_EDGES)        // E
#define WS_HS    (102400 + 2 * E_EDGES)    // N*D/2 ints (bf16 h*norm)
#define WS_FULL_INTS ((size_t)WS_HS + (size_t)N_NODES * D / 2)
#define WS_MID_INTS  ((size_t)WS_HS)

// ======================= fused prep + coarse count =======================
// blocks < prep_blocks: hs = bf16(h * norm_src)   (skipped when prep_blocks==0)
// remaining blocks: LDS histogram of dst>>7 into cnt (int4-vectorized reads)
__global__ __launch_bounds__(256) void prep_count(const float* __restrict__ h,
                                                  const float* __restrict__ norm,
                                                  unsigned short* __restrict__ hs,
                                                  const int* __restrict__ dst,
                                                  int* __restrict__ cnt,
                                                  int prep_blocks) {
    __shared__ int hist[NB];
    const int t = threadIdx.x;
    if ((int)blockIdx.x < prep_blocks) {
        const int idx = blockIdx.x * 256 + t;
        const int node = idx >> 5;
        const int c = (idx & 31) << 2;
        const float nv = norm[node];
        const float4 v = *reinterpret_cast<const float4*>(h + node * D + c);
        float a[4] = {v.x * nv, v.y * nv, v.z * nv, v.w * nv};
        ushort4 o;
        unsigned short* op = reinterpret_cast<unsigned short*>(&o);
        #pragma unroll
        for (int i = 0; i < 4; ++i) {
            unsigned int u = __float_as_uint(a[i]);
            u += 0x7FFFu + ((u >> 16) & 1u);            // round-to-nearest-even
            op[i] = (unsigned short)(u >> 16);
        }
        *reinterpret_cast<ushort4*>(hs + node * D + c) = o;
        return;
    }
    const int cb = blockIdx.x - prep_blocks;
    const int e0 = cb * CNT_CHUNK;
    const int rem = (E_EDGES - e0 < CNT_CHUNK) ? (E_EDGES - e0) : CNT_CHUNK;
    for (int i = t; i < NB; i += 256) hist[i] = 0;
    __syncthreads();
    if (rem == CNT_CHUNK) {
        const int4* d4 = reinterpret_cast<const int4*>(dst + e0);
        #pragma unroll
        for (int p = 0; p < 2; ++p) {
            const int4 v = d4[p * 256 + t];
            atomicAdd(&hist[v.x >> SHIFT], 1);
            atomicAdd(&hist[v.y >> SHIFT], 1);
            atomicAdd(&hist[v.z >> SHIFT], 1);
            atomicAdd(&hist[v.w >> SHIFT], 1);
        }
    } else {
        for (int i = t; i < rem; i += 256)
            atomicAdd(&hist[dst[e0 + i] >> SHIFT], 1);
    }
    __syncthreads();
    for (int b = t; b < NB; b += 256) {
        const int c = hist[b];
        if (c) atomicAdd(&cnt[b], c);
    }
}

// ======================= scan 782 bin counts =======================
__global__ __launch_bounds__(1024) void coarse_scan(const int* __restrict__ cnt,
                                                    int* __restrict__ boff,
                                                    int* __restrict__ pos) {
    __shared__ int buf[2][1024];
    const int t = threadIdx.x;
    const int v = (t < NB) ? cnt[t] : 0;
    int pi = 0;
    buf[0][t] = v;
    __syncthreads();
    #pragma unroll
    for (int o = 1; o < 1024; o <<= 1) {
        const int nv = buf[pi][t] + (t >= o ? buf[pi][t - o] : 0);
        buf[1 - pi][t] = nv;
        pi = 1 - pi;
        __syncthreads();
    }
    if (t < NB) {
        const int excl = buf[pi][t] - v;
        boff[t] = excl;
        pos[t] = excl;
    }
    if (t == 0) boff[NB] = E_EDGES;
}

// ======================= scatter packed words by coarse bin =======================
__global__ __launch_bounds__(1024) void coarse_scatter(const int* __restrict__ src,
                                                       const int* __restrict__ dst,
                                                       int* __restrict__ pos,
                                                       int* __restrict__ ebuf) {
    __shared__ int hist[NB];
    const int t = threadIdx.x;
    const int e0 = blockIdx.x * SCAT_CHUNK;
    const int rem = (E_EDGES - e0 < SCAT_CHUNK) ? (E_EDGES - e0) : SCAT_CHUNK;
    for (int i = t; i < NB; i += 1024) hist[i] = 0;
    __syncthreads();
    if (rem == SCAT_CHUNK) {
        const int4* d4 = reinterpret_cast<const int4*>(dst + e0);
        #pragma unroll
        for (int p = 0; p < 4; ++p) {
            const int4 v = d4[p * 1024 + t];
            atomicAdd(&hist[v.x >> SHIFT], 1);
            atomicAdd(&hist[v.y >> SHIFT], 1);
            atomicAdd(&hist[v.z >> SHIFT], 1);
            atomicAdd(&hist[v.w >> SHIFT], 1);
        }
    } else {
        for (int i = t; i < rem; i += 1024)
            atomicAdd(&hist[dst[e0 + i] >> SHIFT], 1);
    }
    __syncthreads();
    for (int b = t; b < NB; b += 1024) {
        const int c = hist[b];
        if (c) hist[b] = atomicAdd(&pos[b], c);
    }
    __syncthreads();
    if (rem == SCAT_CHUNK) {
        const int4* d4 = reinterpret_cast<const int4*>(dst + e0);
        const int4* s4 = reinterpret_cast<const int4*>(src + e0);
        #pragma unroll
        for (int p = 0; p < 4; ++p) {
            const int4 dv = d4[p * 1024 + t];
            const int4 sv = s4[p * 1024 + t];
            int pz;
            pz = atomicAdd(&hist[dv.x >> SHIFT], 1);
            ebuf[pz] = (sv.x << SHIFT) | (dv.x & (BNODES - 1));
            pz = atomicAdd(&hist[dv.y >> SHIFT], 1);
            ebuf[pz] = (sv.y << SHIFT) | (dv.y & (BNODES - 1));
            pz = atomicAdd(&hist[dv.z >> SHIFT], 1);
            ebuf[pz] = (sv.z << SHIFT) | (dv.z & (BNODES - 1));
            pz = atomicAdd(&hist[dv.w >> SHIFT], 1);
            ebuf[pz] = (sv.w << SHIFT) | (dv.w & (BNODES - 1));
        }
    } else {
        for (int i = t; i < rem; i += 1024) {
            const int d = dst[e0 + i];
            const int b = d >> SHIFT;
            const int p = atomicAdd(&hist[b], 1);
            ebuf[p] = (src[e0 + i] << SHIFT) | (d & (BNODES - 1));
        }
    }
}

// ======================= per-bin counting sort -> node CSR =======================
__global__ __launch_bounds__(256) void bin_sort(const int* __restrict__ boff,
                                                const int* __restrict__ ebuf,
                                                int* __restrict__ esrc,
                                                int* __restrict__ noff) {
    __shared__ int hist[BNODES];
    __shared__ int curs[BNODES];
    __shared__ int sbuf[2][BNODES];
    const int t = threadIdx.x;
    const int bin = blockIdx.x;
    if (t < BNODES) hist[t] = 0;
    __syncthreads();
    const int b0 = boff[bin];
    const int b1 = boff[bin + 1];
    for (int i = b0 + t; i < b1; i += 256)
        atomicAdd(&hist[ebuf[i] & (BNODES - 1)], 1);
    __syncthreads();
    if (t < BNODES) sbuf[0][t] = hist[t];
    __syncthreads();
    int pi = 0;
    #pragma unroll
    for (int o = 1; o < BNODES; o <<= 1) {
        if (t < BNODES)
            sbuf[1 - pi][t] = sbuf[pi][t] + (t >= o ? sbuf[pi][t - o] : 0);
        pi = 1 - pi;
        __syncthreads();
    }
    if (t < BNODES) {
        const int base = b0 + sbuf[pi][t] - hist[t];
        curs[t] = base;
        const int node = (bin << SHIFT) + t;
        if (node < N_NODES) noff[node] = base;
    }
    if (bin == 0 && t == 0) noff[N_NODES] = E_EDGES;
    __syncthreads();
    for (int i = b0 + t; i < b1; i += 256) {
        const int w = ebuf[i];
        const int p = atomicAdd(&curs[w & (BNODES - 1)], 1);
        esrc[p] = w >> SHIFT;
    }
}

// ======================= wprep body (shared by gather kernels) =======================
// Whs[(kiter*8+nt)*64 + lane] = W[kiter*32 + (lane>>4)*8 + j][nt*16 + (lane&15)], j=0..7
__device__ __forceinline__ void wprep_body(int tid, const float* __restrict__ Wm,
                                           f16x8* __restrict__ Whs) {
    const int kiter = tid >> 9;
    const int nt = (tid >> 6) & 7;
    const int lane = tid & 63;
    const int q = lane >> 4;
    const int col = nt * 16 + (lane & 15);
    f16x8 v;
    #pragma unroll
    for (int j = 0; j < 8; ++j)
        v[j] = (_Float16)Wm[(kiter * 32 + q * 8 + j) * D + col];
    Whs[tid] = v;
}

// ======================= gather (bf16) + fused wprep =======================
// 16 lanes per node, 16 B loads, 4 rows in flight. Blocks >= GATH_NBLK do wprep
// (safe: ebuf-aliased Whs is dead after bin_sort; gather reads only esrc/noff).
__global__ __launch_bounds__(256) void gather_wprep(
    const unsigned short* __restrict__ hs, const int* __restrict__ noff,
    const int* __restrict__ esrc, float* __restrict__ g,
    const float* __restrict__ Wm, f16x8* __restrict__ Whs)
{
    if ((int)blockIdx.x >= GATH_NBLK) {
        wprep_body((blockIdx.x - GATH_NBLK) * 256 + threadIdx.x, Wm, Whs);
        return;
    }
    const int t = threadIdx.x;
    const int node = blockIdx.x * 16 + (t >> 4);
    const int c = (t & 15) << 3;                    // 8 cols per lane
    const int beg = noff[node];
    const int end = noff[node + 1];
    float a[8];
    #pragma unroll
    for (int j = 0; j < 8; ++j) a[j] = 0.f;
    int i = beg;
    for (; i + 3 < end; i += 4) {
        const int s0 = esrc[i];
        const int s1 = esrc[i + 1];
        const int s2 = esrc[i + 2];
        const int s3 = esrc[i + 3];
        const u16x8 u0 = *reinterpret_cast<const u16x8*>(hs + s0 * D + c);
        const u16x8 u1 = *reinterpret_cast<const u16x8*>(hs + s1 * D + c);
        const u16x8 u2 = *reinterpret_cast<const u16x8*>(hs + s2 * D + c);
        const u16x8 u3 = *reinterpret_cast<const u16x8*>(hs + s3 * D + c);
        #pragma unroll
        for (int j = 0; j < 8; ++j) {
            a[j] += __uint_as_float((unsigned int)u0[j] << 16);
            a[j] += __uint_as_float((unsigned int)u1[j] << 16);
            a[j] += __uint_as_float((unsigned int)u2[j] << 16);
            a[j] += __uint_as_float((unsigned int)u3[j] << 16);
        }
    }
    for (; i < end; ++i) {
        const int s = esrc[i];
        const u16x8 u = *reinterpret_cast<const u16x8*>(hs + s * D + c);
        #pragma unroll
        for (int j = 0; j < 8; ++j)
            a[j] += __uint_as_float((unsigned int)u[j] << 16);
    }
    float4 v0, v1;
    v0.x = a[0]; v0.y = a[1]; v0.z = a[2]; v0.w = a[3];
    v1.x = a[4]; v1.y = a[5]; v1.z = a[6]; v1.w = a[7];
    *reinterpret_cast<float4*>(g + node * D + c) = v0;
    *reinterpret_cast<float4*>(g + node * D + c + 4) = v1;
}

// ======================= gather (fp32, mid tier) + fused wprep =======================
__global__ __launch_bounds__(256) void gather_fp32(const float* __restrict__ h,
                                                   const float* __restrict__ norm,
                                                   const int* __restrict__ noff,
                                                   const int* __restrict__ esrc,
                                                   float* __restrict__ g,
                                                   const float* __restrict__ Wm,
                                                   f16x8* __restrict__ Whs) {
    if ((int)blockIdx.x >= GATH32_NBLK) {
        wprep_body((blockIdx.x - GATH32_NBLK) * 256 + threadIdx.x, Wm, Whs);
        return;
    }
    const int t = threadIdx.x;
    const int node = blockIdx.x * 8 + (t >> 5);
    const int c = (t & 31) << 2;
    const int beg = noff[node];
    const int end = noff[node + 1];
    float4 acc = make_float4(0.f, 0.f, 0.f, 0.f);
    for (int i = beg; i < end; ++i) {
        const int s = esrc[i];
        const float nv = norm[s];
        const float4 hv = *reinterpret_cast<const float4*>(h + s * D + c);
        acc.x += hv.x * nv;
        acc.y += hv.y * nv;
        acc.z += hv.z * nv;
        acc.w += hv.w * nv;
    }
    *reinterpret_cast<float4*>(g + node * D + c) = acc;
}

// ======================= tier-0 fallback: atomic scatter =======================
__global__ __launch_bounds__(256) void scatter_kernel(
    const float* __restrict__ h, const float* __restrict__ norm,
    const int* __restrict__ src, const int* __restrict__ dst,
    float* __restrict__ g)
{
    const int idx = blockIdx.x * 256 + threadIdx.x;
    const int e = idx >> 5;
    const int c = (idx & 31) << 2;
    const int s = src[e];
    const int d = dst[e];
    const float nv = norm[s];
    const float4 hv = *reinterpret_cast<const float4*>(h + s * D + c);
    float* gp = g + d * D + c;
    atomicAdd(gp + 0, hv.x * nv);
    atomicAdd(gp + 1, hv.y * nv);
    atomicAdd(gp + 2, hv.z * nv);
    atomicAdd(gp + 3, hv.w * nv);
}

// ======================= MFMA GEMM + epilogue (round-6 proven) =======================
__global__ __launch_bounds__(256) void gemm_mfma(
    float* __restrict__ out, const f16x8* __restrict__ Whs,
    const float* __restrict__ bias, const float* __restrict__ norm)
{
    __shared__ f16x8 Wlds[2048];           // 32 KB
    const int t = threadIdx.x;
    const int row0 = blockIdx.x * 64;

    #pragma unroll
    for (int p = 0; p < 8; ++p)
        reinterpret_cast<float4*>(Wlds)[p * 256 + t] =
            reinterpret_cast<const float4*>(Whs)[p * 256 + t];
    __syncthreads();

    const int lane = t & 63;
    const int strip = t >> 6;
    const int q = lane >> 4;
    const int l15 = lane & 15;

    int mrow = row0 + strip * 16 + l15;
    if (mrow >= N_NODES) mrow = N_NODES - 1;

    f32x4 acc[8];
    #pragma unroll
    for (int i = 0; i < 8; ++i) acc[i] = (f32x4){0.f, 0.f, 0.f, 0.f};

    #pragma unroll
    for (int kiter = 0; kiter < 4; ++kiter) {
        const float* gp = out + mrow * D + kiter * 32 + q * 8;
        const float4 ga = *reinterpret_cast<const float4*>(gp);
        const float4 gb = *reinterpret_cast<const float4*>(gp + 4);
        f16x8 a;
        a[0] = (_Float16)ga.x; a[1] = (_Float16)ga.y;
        a[2] = (_Float16)ga.z; a[3] = (_Float16)ga.w;
        a[4] = (_Float16)gb.x; a[5] = (_Float16)gb.y;
        a[6] = (_Float16)gb.z; a[7] = (_Float16)gb.w;
        #pragma unroll
        for (int nt = 0; nt < 8; ++nt) {
            const f16x8 b = Wlds[(kiter * 8 + nt) * 64 + lane];
            acc[nt] = __builtin_amdgcn_mfma_f32_16x16x32_f16(a, b, acc[nt], 0, 0, 0);
        }
    }

    float nrm[4];
    int mr[4];
    #pragma unroll
    for (int rgi = 0; rgi < 4; ++rgi) {
        mr[rgi] = row0 + strip * 16 + q * 4 + rgi;
        nrm[rgi] = (mr[rgi] < N_NODES) ? norm[mr[rgi]] : 0.f;
    }
    #pragma unroll
    for (int nt = 0; nt < 8; ++nt) {
        const int col = nt * 16 + l15;
        const float bc = bias[col];
        #pragma unroll
        for (int rgi = 0; rgi < 4; ++rgi) {
            if (mr[rgi] < N_NODES) {
                float v = acc[nt][rgi] * nrm[rgi] + bc;
                v = v > 0.f ? v : 0.2f * v;
                out[mr[rgi] * D + col] = v;
            }
        }
    }
}

// ======================= fp32 GEMM (tier-0 fallback only) =======================
__global__ __launch_bounds__(256) void gemm_epilogue(
    float* __restrict__ out, const float* __restrict__ Wm,
    const float* __restrict__ bias, const float* __restrict__ norm)
{
    __shared__ float gs[GROWS][D + 4];
    __shared__ float Wlds[KCH][D];
    const int t = threadIdx.x;
    const int row0 = blockIdx.x * GROWS;

    #pragma unroll
    for (int p = 0; p < 8; ++p) {
        const int i = p * 256 + t;
        const int r = i >> 5;
        const int c = (i & 31) << 2;
        int gr = row0 + r;
        if (gr >= N_NODES) gr = N_NODES - 1;
        const float4 v = *reinterpret_cast<const float4*>(out + gr * D + c);
        *reinterpret_cast<float4*>(&gs[r][c]) = v;
    }

    const int rg = (t >> 5) * 8;
    const int cb = (t & 31) << 2;

    float4 acc[8];
    #pragma unroll
    for (int i = 0; i < 8; ++i) acc[i] = make_float4(0.f, 0.f, 0.f, 0.f);

    for (int kc = 0; kc < D; kc += KCH) {
        __syncthreads();
        #pragma unroll
        for (int p = 0; p < 4; ++p) {
            const int i = p * 256 + t;
            const int kk = i >> 5;
            const int c = (i & 31) << 2;
            *reinterpret_cast<float4*>(&Wlds[kk][c]) =
                *reinterpret_cast<const float4*>(Wm + (kc + kk) * D + c);
        }
        __syncthreads();

        #pragma unroll
        for (int k4 = 0; k4 < KCH; k4 += 4) {
            float4 wv[4];
            #pragma unroll
            for (int kk = 0; kk < 4; ++kk)
                wv[kk] = *reinterpret_cast<const float4*>(&Wlds[k4 + kk][cb]);
            #pragma unroll
            for (int i = 0; i < 8; ++i) {
                const float4 gv = *reinterpret_cast<const float4*>(&gs[rg + i][kc + k4]);
                acc[i].x += gv.x * wv[0].x; acc[i].y += gv.x * wv[0].y;
                acc[i].z += gv.x * wv[0].z; acc[i].w += gv.x * wv[0].w;
                acc[i].x += gv.y * wv[1].x; acc[i].y += gv.y * wv[1].y;
                acc[i].z += gv.y * wv[1].z; acc[i].w += gv.y * wv[1].w;
                acc[i].x += gv.z * wv[2].x; acc[i].y += gv.z * wv[2].y;
                acc[i].z += gv.z * wv[2].z; acc[i].w += gv.z * wv[2].w;
                acc[i].x += gv.w * wv[3].x; acc[i].y += gv.w * wv[3].y;
                acc[i].z += gv.w * wv[3].z; acc[i].w += gv.w * wv[3].w;
            }
        }
    }

    const float4 b = *reinterpret_cast<const float4*>(bias + cb);
    #pragma unroll
    for (int i = 0; i < 8; ++i) {
        const int gr = row0 + rg + i;
        if (gr < N_NODES) {
            const float nv = norm[gr];
            float4 v;
            v.x = acc[i].x * nv + b.x;
            v.y = acc[i].y * nv + b.y;
            v.z = acc[i].z * nv + b.z;
            v.w = acc[i].w * nv + b.w;
            v.x = v.x > 0.f ? v.x : 0.2f * v.x;
            v.y = v.y > 0.f ? v.y : 0.2f * v.y;
            v.z = v.z > 0.f ? v.z : 0.2f * v.z;
            v.w = v.w > 0.f ? v.w : 0.2f * v.w;
            *reinterpret_cast<float4*>(out + gr * D + cb) = v;
        }
    }
}

extern "C" void kernel_launch(void* const* d_in, const int* in_sizes, int n_in,
                              void* d_out, int out_size, void* d_ws, size_t ws_size,
                              hipStream_t stream) {
    const float* h    = (const float*)d_in[0];
    const float* norm = (const float*)d_in[1];
    const float* Wm   = (const float*)d_in[2];
    const float* bias = (const float*)d_in[3];
    const int*   src  = (const int*)d_in[4];
    const int*   dst  = (const int*)d_in[5];
    float* out = (float*)d_out;
    int* ws = (int*)d_ws;

    if (ws_size >= WS_MID_INTS * 4) {
        int* cnt  = ws + WS_CNT;
        int* boff = ws + WS_BOFF;
        int* pos  = ws + WS_POS;
        int* noff = ws + WS_NOFF;
        int* ebuf = ws + WS_EBUF;
        int* esrc = ws + WS_ESRC;
        unsigned short* hs = (unsigned short*)(ws + WS_HS);
        f16x8* Whs = (f16x8*)ebuf;         // ebuf dead after bin_sort
        const bool use_bf16 = (ws_size >= WS_FULL_INTS * 4);

        hipMemsetAsync(cnt, 0, NB * sizeof(int), stream);
        if (use_bf16) {
            prep_count<<<PREP_NBLK + CNT_NBLK, 256, 0, stream>>>(h, norm, hs, dst, cnt, PREP_NBLK);
        } else {
            prep_count<<<CNT_NBLK, 256, 0, stream>>>(h, norm, hs, dst, cnt, 0);
        }
        coarse_scan   <<<1, 1024, 0, stream>>>(cnt, boff, pos);
        coarse_scatter<<<SCAT_NBLK, 1024, 0, stream>>>(src, dst, pos, ebuf);
        bin_sort      <<<NB, 256, 0, stream>>>(boff, ebuf, esrc, noff);
        if (use_bf16)
            gather_wprep<<<GATH_NBLK + 8, 256, 0, stream>>>(hs, noff, esrc, out, Wm, Whs);
        else
            gather_fp32<<<GATH32_NBLK + 8, 256, 0, stream>>>(h, norm, noff, esrc, out, Wm, Whs);
        gemm_mfma<<<(N_NODES + 63) / 64, 256, 0, stream>>>(out, Whs, bias, norm);
    } else {
        hipMemsetAsync(out, 0, (size_t)N_NODES * D * sizeof(float), stream);
        scatter_kernel<<<(E_EDGES * 32) / 256, 256, 0, stream>>>(h, norm, src, dst, out);
        gemm_epilogue<<<(N_NODES + GROWS - 1) / GROWS, 256, 0, stream>>>(out, Wm, bias, norm);
    }
}